// Round 3
// baseline (4035.744 us; speedup 1.0000x reference)
//
#include <hip/hip_runtime.h>
#include <hip/hip_bf16.h>

// GLATE: 3-layer GraphSAGE encoder x2 graphs, f32 end-to-end baseline.
// N=50000 nodes, E=400000 edges, DIN=128, D=512.

#define NN 50000
#define NE 400000
#define DIN 128
#define DH 512

// ---------------- CSR build ----------------

__global__ void k_zero_int(int* __restrict__ p, int n) {
    int i = blockIdx.x * 256 + threadIdx.x;
    if (i < n) p[i] = 0;
}

__global__ void k_deg(const int* __restrict__ dst, int* __restrict__ deg, int E) {
    int e = blockIdx.x * 256 + threadIdx.x;
    if (e < E) atomicAdd(&deg[dst[e]], 1);
}

// single-block exclusive scan over n counters -> rowptr[0..n], cursor copy
__global__ void k_scan(const int* __restrict__ deg, int* __restrict__ rowptr,
                       int* __restrict__ cursor, int n) {
    __shared__ int buf[1024];
    __shared__ int carry;
    if (threadIdx.x == 0) carry = 0;
    __syncthreads();
    for (int base = 0; base < n; base += 1024) {
        int i = base + (int)threadIdx.x;
        int v = (i < n) ? deg[i] : 0;
        buf[threadIdx.x] = v;
        __syncthreads();
        for (int off = 1; off < 1024; off <<= 1) {
            int t = (threadIdx.x >= off) ? buf[threadIdx.x - off] : 0;
            __syncthreads();
            buf[threadIdx.x] += t;
            __syncthreads();
        }
        int excl = buf[threadIdx.x] - v;
        if (i < n) { rowptr[i] = carry + excl; cursor[i] = carry + excl; }
        __syncthreads();
        if (threadIdx.x == 1023) carry += buf[1023];
        __syncthreads();
    }
    if (threadIdx.x == 0) rowptr[n] = carry;
}

__global__ void k_fill(const int* __restrict__ src, const int* __restrict__ dst,
                       int* __restrict__ cursor, int* __restrict__ col, int E) {
    int e = blockIdx.x * 256 + threadIdx.x;
    if (e < E) {
        int p = atomicAdd(&cursor[dst[e]], 1);
        col[p] = src[e];
    }
}

// ---------------- mean aggregation (CSR) ----------------
// one block per node; TPB = D/2 threads; float2 per thread
template<int D, int TPB>
__global__ __launch_bounds__(TPB) void k_agg_mean(
        const float* __restrict__ x, const int* __restrict__ rowptr,
        const int* __restrict__ col, float* __restrict__ mean) {
    int node = blockIdx.x;
    int s = rowptr[node], e = rowptr[node + 1];
    int t = threadIdx.x;
    const float2* x2 = (const float2*)x;
    float2 acc = make_float2(0.f, 0.f);
    for (int j = s; j < e; ++j) {
        int r = col[j];
        float2 v = x2[(size_t)r * (D / 2) + t];
        acc.x += v.x; acc.y += v.y;
    }
    float invc = (e > s) ? 1.0f / (float)(e - s) : 0.0f;
    ((float2*)mean)[(size_t)node * (D / 2) + t] = make_float2(acc.x * invc, acc.y * invc);
}

// ---------------- layer-1 fused kernel ----------------
// 64x64 tile, 256 threads, 4x4 microtile, 3 accumulator sets.
// acc_h = x@Wr + mean@Wl ; acc1 = x@W_w ; acc2 = x@W2_w
// h = prelu(acc_h + bl); xin2 = h + acc1 + Wb; xp3 = h + acc2 + W2b
__global__ __launch_bounds__(256) void k_gemm1(
        const float* __restrict__ x, const float* __restrict__ mean,
        const float* __restrict__ Wr, const float* __restrict__ Wl,
        const float* __restrict__ Ww, const float* __restrict__ Ww2,
        const float* __restrict__ bl, const float* __restrict__ Wb,
        const float* __restrict__ W2b, const float* __restrict__ prelu_a,
        float* __restrict__ xin2, float* __restrict__ xp3, int M) {
    __shared__ float As[16][64];
    __shared__ float Bs0[16][64];
    __shared__ float Bs1[16][64];
    __shared__ float Bs2[16][64];

    int m0 = blockIdx.x * 64;
    int n0 = blockIdx.y * 64;
    int tid = threadIdx.x;
    int tr = tid / 16, tc = tid % 16;

    float acch[4][4] = {};
    float acc1[4][4] = {};
    float acc2[4][4] = {};

    // A tile load index: row = tid/4 (0..63), kq = tid%4
    int lrow = tid >> 2, lkq = tid & 3;
    // B tile load index: k = tid/16, nq = tid%16
    int lk = tid >> 4, lnq = tid & 15;

    // ---- phase X: A = x (K=128), three B matrices ----
    for (int k0 = 0; k0 < DIN; k0 += 16) {
        float4 av = make_float4(0, 0, 0, 0);
        int gr = m0 + lrow;
        if (gr < M) av = *(const float4*)&x[(size_t)gr * DIN + k0 + lkq * 4];
        As[lkq * 4 + 0][lrow] = av.x; As[lkq * 4 + 1][lrow] = av.y;
        As[lkq * 4 + 2][lrow] = av.z; As[lkq * 4 + 3][lrow] = av.w;
        size_t boff = (size_t)(k0 + lk) * DH + n0 + lnq * 4;
        *(float4*)&Bs0[lk][lnq * 4] = *(const float4*)&Wr[boff];
        *(float4*)&Bs1[lk][lnq * 4] = *(const float4*)&Ww[boff];
        *(float4*)&Bs2[lk][lnq * 4] = *(const float4*)&Ww2[boff];
        __syncthreads();
#pragma unroll
        for (int kk = 0; kk < 16; ++kk) {
            float a[4], b0[4], b1[4], b2[4];
            *(float4*)a  = *(float4*)&As[kk][tr * 4];
            *(float4*)b0 = *(float4*)&Bs0[kk][tc * 4];
            *(float4*)b1 = *(float4*)&Bs1[kk][tc * 4];
            *(float4*)b2 = *(float4*)&Bs2[kk][tc * 4];
#pragma unroll
            for (int i = 0; i < 4; ++i)
#pragma unroll
                for (int j = 0; j < 4; ++j) {
                    acch[i][j] += a[i] * b0[j];
                    acc1[i][j] += a[i] * b1[j];
                    acc2[i][j] += a[i] * b2[j];
                }
        }
        __syncthreads();
    }
    // ---- phase M: A = mean (K=128), B = Wl, into acch ----
    for (int k0 = 0; k0 < DIN; k0 += 16) {
        float4 av = make_float4(0, 0, 0, 0);
        int gr = m0 + lrow;
        if (gr < M) av = *(const float4*)&mean[(size_t)gr * DIN + k0 + lkq * 4];
        As[lkq * 4 + 0][lrow] = av.x; As[lkq * 4 + 1][lrow] = av.y;
        As[lkq * 4 + 2][lrow] = av.z; As[lkq * 4 + 3][lrow] = av.w;
        *(float4*)&Bs0[lk][lnq * 4] = *(const float4*)&Wl[(size_t)(k0 + lk) * DH + n0 + lnq * 4];
        __syncthreads();
#pragma unroll
        for (int kk = 0; kk < 16; ++kk) {
            float a[4], b0[4];
            *(float4*)a  = *(float4*)&As[kk][tr * 4];
            *(float4*)b0 = *(float4*)&Bs0[kk][tc * 4];
#pragma unroll
            for (int i = 0; i < 4; ++i)
#pragma unroll
                for (int j = 0; j < 4; ++j)
                    acch[i][j] += a[i] * b0[j];
        }
        __syncthreads();
    }

    float aslope = *prelu_a;
    int colb = n0 + tc * 4;
    float4 vbl  = *(const float4*)&bl[colb];
    float4 vwb  = *(const float4*)&Wb[colb];
    float4 vw2b = *(const float4*)&W2b[colb];
#pragma unroll
    for (int i = 0; i < 4; ++i) {
        int gr = m0 + tr * 4 + i;
        if (gr >= M) continue;
        float hb[4] = { vbl.x, vbl.y, vbl.z, vbl.w };
        float wb[4] = { vwb.x, vwb.y, vwb.z, vwb.w };
        float w2b[4] = { vw2b.x, vw2b.y, vw2b.z, vw2b.w };
        float4 o1, o2;
        float* p1 = &o1.x; float* p2 = &o2.x;
#pragma unroll
        for (int j = 0; j < 4; ++j) {
            float h = acch[i][j] + hb[j];
            h = (h >= 0.f) ? h : aslope * h;
            p1[j] = h + acc1[i][j] + wb[j];
            p2[j] = h + acc2[i][j] + w2b[j];
        }
        *(float4*)&xin2[(size_t)gr * DH + colb] = o1;
        *(float4*)&xp3[(size_t)gr * DH + colb] = o2;
    }
}

// ---------------- layers 2/3 fused GEMM ----------------
// C = [addend +] prelu(Aa@Ba + Ab@Bb + bias), Aa/Ab [M,512], Ba/Bb [512,512]
// 128x128 tile, 256 threads, 8x8 microtile.
template<bool HAS_ADDEND>
__global__ __launch_bounds__(256) void k_gemm2(
        const float* __restrict__ Aa, const float* __restrict__ Ba,
        const float* __restrict__ Ab, const float* __restrict__ Bb,
        const float* __restrict__ bias, const float* __restrict__ addend,
        const float* __restrict__ prelu_a, float* __restrict__ C, int M) {
    __shared__ float As[16][128];
    __shared__ float Bs[16][128];

    int m0 = blockIdx.x * 128;
    int n0 = blockIdx.y * 128;
    int tid = threadIdx.x;
    int tr = tid / 16, tc = tid % 16;

    float acc[8][8] = {};

    for (int p = 0; p < 2; ++p) {
        const float* A = p ? Ab : Aa;
        const float* B = p ? Bb : Ba;
        for (int k0 = 0; k0 < DH; k0 += 16) {
            // A tile: 128 rows x 16 k = 512 float4, 2 per thread
#pragma unroll
            for (int u = 0; u < 2; ++u) {
                int f = tid * 2 + u;
                int row = f >> 2, kq = f & 3;
                int gr = m0 + row;
                float4 v = make_float4(0, 0, 0, 0);
                if (gr < M) v = *(const float4*)&A[(size_t)gr * DH + k0 + kq * 4];
                As[kq * 4 + 0][row] = v.x; As[kq * 4 + 1][row] = v.y;
                As[kq * 4 + 2][row] = v.z; As[kq * 4 + 3][row] = v.w;
            }
            // B tile: 16 k x 128 n = 512 float4, 2 per thread
#pragma unroll
            for (int u = 0; u < 2; ++u) {
                int f = tid * 2 + u;
                int k = f >> 5, nq = f & 31;
                *(float4*)&Bs[k][nq * 4] =
                    *(const float4*)&B[(size_t)(k0 + k) * DH + n0 + nq * 4];
            }
            __syncthreads();
#pragma unroll
            for (int kk = 0; kk < 16; ++kk) {
                float a[8], b[8];
                *(float4*)&a[0] = *(float4*)&As[kk][tr * 8];
                *(float4*)&a[4] = *(float4*)&As[kk][tr * 8 + 4];
                *(float4*)&b[0] = *(float4*)&Bs[kk][tc * 8];
                *(float4*)&b[4] = *(float4*)&Bs[kk][tc * 8 + 4];
#pragma unroll
                for (int i = 0; i < 8; ++i)
#pragma unroll
                    for (int j = 0; j < 8; ++j)
                        acc[i][j] += a[i] * b[j];
            }
            __syncthreads();
        }
    }

    float aslope = *prelu_a;
#pragma unroll
    for (int i = 0; i < 8; ++i) {
        int gr = m0 + tr * 8 + i;
        if (gr >= M) continue;
#pragma unroll
        for (int jq = 0; jq < 2; ++jq) {
            int colb = n0 + tc * 8 + jq * 4;
            float4 vb = *(const float4*)&bias[colb];
            float bb[4] = { vb.x, vb.y, vb.z, vb.w };
            float4 o;
            float* po = &o.x;
            float4 ad = make_float4(0, 0, 0, 0);
            if (HAS_ADDEND) ad = *(const float4*)&addend[(size_t)gr * DH + colb];
            float av[4] = { ad.x, ad.y, ad.z, ad.w };
#pragma unroll
            for (int j = 0; j < 4; ++j) {
                float v = acc[i][jq * 4 + j] + bb[j];
                v = (v >= 0.f) ? v : aslope * v;
                if (HAS_ADDEND) v += av[j];
                po[j] = v;
            }
            *(float4*)&C[(size_t)gr * DH + colb] = o;
        }
    }
}

// ---------------- launch ----------------

extern "C" void kernel_launch(void* const* d_in, const int* in_sizes, int n_in,
                              void* d_out, int out_size, void* d_ws, size_t ws_size,
                              hipStream_t stream) {
    const float* x1 = (const float*)d_in[0];
    const float* x2 = (const float*)d_in[1];
    const int* ei1 = (const int*)d_in[2];
    const int* ei2 = (const int*)d_in[3];
    const float* l1_Wl = (const float*)d_in[4];
    const float* l1_bl = (const float*)d_in[5];
    const float* l1_Wr = (const float*)d_in[6];
    const float* l2_Wl = (const float*)d_in[7];
    const float* l2_bl = (const float*)d_in[8];
    const float* l2_Wr = (const float*)d_in[9];
    const float* l3_Wl = (const float*)d_in[10];
    const float* l3_bl = (const float*)d_in[11];
    const float* l3_Wr = (const float*)d_in[12];
    const float* W_w = (const float*)d_in[13];
    const float* W_b = (const float*)d_in[14];
    const float* W2_w = (const float*)d_in[15];
    const float* W2_b = (const float*)d_in[16];
    const float* prelu_a = (const float*)d_in[17];

    const int M = NN, E = NE;
    const size_t NS = (size_t)NN * DH;   // 25.6M floats

    float* f_ws = (float*)d_ws;
    float* mean = f_ws;                  // [N,512] (layer1 uses first N*128)
    float* xin2 = f_ws + NS;
    float* xp3  = f_ws + 2 * NS;
    float* xin3 = f_ws + 3 * NS;
    int* iws    = (int*)(f_ws + 4 * NS);
    int* deg    = iws;                   // N
    int* rowptr = iws + NN;              // N+1
    int* cursor = iws + 2 * NN + 1;      // N
    int* colx   = iws + 3 * NN + 1;      // E

    float* out = (float*)d_out;

    dim3 g1((M + 63) / 64, DH / 64);
    dim3 g2((M + 127) / 128, DH / 128);

    for (int g = 0; g < 2; ++g) {
        const float* x = g ? x2 : x1;
        const int* ei = g ? ei2 : ei1;
        const int* src = ei;
        const int* dst = ei + E;
        float* z = out + (size_t)g * NS;

        // CSR build (reused across all 3 layers of this graph)
        k_zero_int<<<(M + 255) / 256, 256, 0, stream>>>(deg, M);
        k_deg<<<(E + 255) / 256, 256, 0, stream>>>(dst, deg, E);
        k_scan<<<1, 1024, 0, stream>>>(deg, rowptr, cursor, M);
        k_fill<<<(E + 255) / 256, 256, 0, stream>>>(src, dst, cursor, colx, E);

        // layer 1
        k_agg_mean<DIN, 64><<<M, 64, 0, stream>>>(x, rowptr, colx, mean);
        k_gemm1<<<g1, 256, 0, stream>>>(x, mean, l1_Wr, l1_Wl, W_w, W2_w,
                                        l1_bl, W_b, W2_b, prelu_a, xin2, xp3, M);
        // layer 2
        k_agg_mean<DH, 256><<<M, 256, 0, stream>>>(xin2, rowptr, colx, mean);
        k_gemm2<true><<<g2, 256, 0, stream>>>(mean, l2_Wl, xin2, l2_Wr,
                                              l2_bl, xp3, prelu_a, xin3, M);
        // layer 3
        k_agg_mean<DH, 256><<<M, 256, 0, stream>>>(xin3, rowptr, colx, mean);
        k_gemm2<false><<<g2, 256, 0, stream>>>(mean, l3_Wl, xin3, l3_Wr,
                                               l3_bl, nullptr, prelu_a, z, M);
    }
}

// Round 4
// 1597.528 us; speedup vs baseline: 2.5262x; 2.5262x over previous
//
#include <hip/hip_runtime.h>

// GLATE: 3-layer GraphSAGE encoder x2 graphs.
// Round 4: bf16 MFMA GEMMs (16x16x32, f32 accum), bf16 activation pipeline.
// N=50000, E=400000, DIN=128, D=512.

#define NN 50000
#define NE 400000
#define DIN 128
#define DH 512
#define MPAD 50048   // 391*128, tile-padded row count for A-operand buffers

typedef __attribute__((ext_vector_type(4))) float f32x4;
typedef __attribute__((ext_vector_type(8))) short bf16x8;
typedef unsigned short u16;

__device__ __forceinline__ u16 f2bf(float f) {
    unsigned u = __float_as_uint(f);
    unsigned r = (u + 0x7fff + ((u >> 16) & 1)) >> 16;   // RNE
    return (u16)r;
}
__device__ __forceinline__ float bf2f(u16 b) {
    return __uint_as_float((unsigned)b << 16);
}

__device__ __forceinline__ void gload16(const void* g, void* l) {
    __builtin_amdgcn_global_load_lds(
        (const __attribute__((address_space(1))) unsigned int*)g,
        (__attribute__((address_space(3))) unsigned int*)l, 16, 0, 0);
}

// ---------------- CSR build ----------------

__global__ void k_zero_int(int* __restrict__ p, int n) {
    int i = blockIdx.x * 256 + threadIdx.x;
    if (i < n) p[i] = 0;
}

__global__ void k_deg(const int* __restrict__ dst, int* __restrict__ deg, int E) {
    int e = blockIdx.x * 256 + threadIdx.x;
    if (e < E) atomicAdd(&deg[dst[e]], 1);
}

__global__ void k_scan(const int* __restrict__ deg, int* __restrict__ rowptr,
                       int* __restrict__ cursor, int n) {
    __shared__ int buf[1024];
    __shared__ int carry;
    if (threadIdx.x == 0) carry = 0;
    __syncthreads();
    for (int base = 0; base < n; base += 1024) {
        int i = base + (int)threadIdx.x;
        int v = (i < n) ? deg[i] : 0;
        buf[threadIdx.x] = v;
        __syncthreads();
        for (int off = 1; off < 1024; off <<= 1) {
            int t = (threadIdx.x >= off) ? buf[threadIdx.x - off] : 0;
            __syncthreads();
            buf[threadIdx.x] += t;
            __syncthreads();
        }
        int excl = buf[threadIdx.x] - v;
        if (i < n) { rowptr[i] = carry + excl; cursor[i] = carry + excl; }
        __syncthreads();
        if (threadIdx.x == 1023) carry += buf[1023];
        __syncthreads();
    }
    if (threadIdx.x == 0) rowptr[n] = carry;
}

__global__ void k_fill(const int* __restrict__ src, const int* __restrict__ dst,
                       int* __restrict__ cursor, int* __restrict__ col, int E) {
    int e = blockIdx.x * 256 + threadIdx.x;
    if (e < E) {
        int p = atomicAdd(&cursor[dst[e]], 1);
        col[p] = src[e];
    }
}

// ---------------- f32 -> bf16 cast ----------------

__global__ void k_cast_bf(const float* __restrict__ x, u16* __restrict__ o, int n) {
    int i = (blockIdx.x * 256 + threadIdx.x) * 4;
    if (i + 3 < n) {
        float4 v = *(const float4*)&x[i];
        o[i + 0] = f2bf(v.x); o[i + 1] = f2bf(v.y);
        o[i + 2] = f2bf(v.z); o[i + 3] = f2bf(v.w);
    } else {
        for (int j = i; j < n; ++j) o[j] = f2bf(x[j]);
    }
}

// ---------------- weight transpose + cast: W[K,N] f32 -> Wt[N,K] bf16 ----------------

__global__ void k_wt(const float* __restrict__ W, u16* __restrict__ Wt, int K, int N) {
    __shared__ float t[32][33];
    int bn = blockIdx.x * 32;
    int bk = blockIdx.y * 32;
    int x = threadIdx.x;          // 0..31
    int y = threadIdx.y;          // 0..7
    for (int i = y; i < 32; i += 8) t[i][x] = W[(size_t)(bk + i) * N + bn + x];
    __syncthreads();
    for (int i = y; i < 32; i += 8)
        Wt[(size_t)(bn + i) * K + bk + x] = f2bf(t[x][i]);
}

// ---------------- mean aggregation over CSR, bf16 in/out, f32 accum ----------------
// one wave per node, 4 nodes per block

template<int D>
__global__ __launch_bounds__(256) void k_agg_bf(
        const u16* __restrict__ x, const int* __restrict__ rowptr,
        const int* __restrict__ col, u16* __restrict__ mean, int n) {
    int node = blockIdx.x * 4 + (threadIdx.x >> 6);
    if (node >= n) return;
    int lane = threadIdx.x & 63;
    int s = rowptr[node], e = rowptr[node + 1];
    float inv = (e > s) ? 1.0f / (float)(e - s) : 0.0f;
    if (D == 512) {
        float acc[8] = {};
        for (int j = s; j < e; ++j) {
            int r = col[j];
            uint4 v = *(const uint4*)(x + (size_t)r * D + lane * 8);
            unsigned w[4] = { v.x, v.y, v.z, v.w };
#pragma unroll
            for (int q = 0; q < 4; ++q) {
                acc[2 * q + 0] += bf2f((u16)(w[q] & 0xffff));
                acc[2 * q + 1] += bf2f((u16)(w[q] >> 16));
            }
        }
        unsigned o[4];
#pragma unroll
        for (int q = 0; q < 4; ++q)
            o[q] = (unsigned)f2bf(acc[2 * q] * inv) |
                   ((unsigned)f2bf(acc[2 * q + 1] * inv) << 16);
        *(uint4*)(mean + (size_t)node * D + lane * 8) = make_uint4(o[0], o[1], o[2], o[3]);
    } else {  // D == 128: 2 bf16 per lane
        float a0 = 0.f, a1 = 0.f;
        for (int j = s; j < e; ++j) {
            int r = col[j];
            unsigned v = *(const unsigned*)(x + (size_t)r * D + lane * 2);
            a0 += bf2f((u16)(v & 0xffff));
            a1 += bf2f((u16)(v >> 16));
        }
        unsigned o = (unsigned)f2bf(a0 * inv) | ((unsigned)f2bf(a1 * inv) << 16);
        *(unsigned*)(mean + (size_t)node * D + lane * 2) = o;
    }
}

// ---------------- MFMA GEMM ----------------
// C[M,512] = maybe_prelu( A1@B1t' [+ A2@B2t'] + bias ) [+ addend]
// A row-major [M,K] bf16 (rows padded to MPAD); Bt row-major [512,K] bf16.
// 128x128 block tile, 256 threads = 4 waves (2x2), each wave 64x64 = 4x4 frags
// of 16x16, BK=32, global_load_lds(16B) staging, linear LDS.

#define MFMA_BF16(a, b, c) __builtin_amdgcn_mfma_f32_16x16x32_bf16(a, b, c, 0, 0, 0)

template<int K1, int K2, bool PRELU, bool ADDEND, bool OUTF32>
__global__ __launch_bounds__(256) void k_mfma(
        const u16* __restrict__ A1, const u16* __restrict__ B1t,
        const u16* __restrict__ A2, const u16* __restrict__ B2t,
        const float* __restrict__ bias, const u16* __restrict__ addend,
        const float* __restrict__ prelu_a,
        float* __restrict__ Cf, u16* __restrict__ Cb, int M) {
    __shared__ __align__(16) u16 As[128 * 32];
    __shared__ __align__(16) u16 Bs[128 * 32];

    int tid = threadIdx.x;
    int wid = tid >> 6, lane = tid & 63;
    int wm = wid >> 1, wn = wid & 1;
    int m0 = blockIdx.x * 128, n0 = blockIdx.y * 128;

    f32x4 acc[4][4];
#pragma unroll
    for (int mi = 0; mi < 4; ++mi)
#pragma unroll
        for (int ni = 0; ni < 4; ++ni)
            acc[mi][ni] = (f32x4){0.f, 0.f, 0.f, 0.f};

    const int lm = lane & 15;      // frag row/col within 16
    const int ko = (lane >> 4) * 8; // k element offset within BK=32

#pragma unroll 1
    for (int ph = 0; ph < ((K2 > 0) ? 2 : 1); ++ph) {
        const u16* A = (ph && K2 > 0) ? A2 : A1;
        const u16* Bt = (ph && K2 > 0) ? B2t : B1t;
        const int K = (ph && K2 > 0) ? K2 : K1;
        for (int k0 = 0; k0 < K; k0 += 32) {
            // stage A,B tiles: thread t handles 16B chunks f = t, t+256
#pragma unroll
            for (int i = 0; i < 2; ++i) {
                int f = tid + i * 256;
                int row = f >> 2, seg = f & 3;
                char* ldst = (char*)nullptr;
                (void)ldst;
                gload16(A + (size_t)(m0 + row) * K + k0 + seg * 8,
                        (char*)As + wid * 1024 + i * 4096);
                gload16(Bt + (size_t)(n0 + row) * K + k0 + seg * 8,
                        (char*)Bs + wid * 1024 + i * 4096);
            }
            __syncthreads();

            bf16x8 af[4], bfr[4];
#pragma unroll
            for (int x = 0; x < 4; ++x) {
                af[x]  = *(const bf16x8*)&As[(wm * 64 + x * 16 + lm) * 32 + ko];
                bfr[x] = *(const bf16x8*)&Bs[(wn * 64 + x * 16 + lm) * 32 + ko];
            }
#pragma unroll
            for (int mi = 0; mi < 4; ++mi)
#pragma unroll
                for (int ni = 0; ni < 4; ++ni)
                    acc[mi][ni] = MFMA_BF16(af[mi], bfr[ni], acc[mi][ni]);
            __syncthreads();
        }
    }

    float aslope = PRELU ? *prelu_a : 0.f;
#pragma unroll
    for (int ni = 0; ni < 4; ++ni) {
        int colv = n0 + wn * 64 + ni * 16 + lm;
        float bv = bias[colv];
#pragma unroll
        for (int mi = 0; mi < 4; ++mi) {
            int rbase = m0 + wm * 64 + mi * 16 + (lane >> 4) * 4;
#pragma unroll
            for (int r = 0; r < 4; ++r) {
                int gr = rbase + r;
                if (gr >= M) continue;
                float v = acc[mi][ni][r] + bv;
                if (PRELU) v = (v >= 0.f) ? v : aslope * v;
                if (ADDEND) v += bf2f(addend[(size_t)gr * DH + colv]);
                if (OUTF32) Cf[(size_t)gr * DH + colv] = v;
                else        Cb[(size_t)gr * DH + colv] = f2bf(v);
            }
        }
    }
}

// ---------------- launch ----------------

extern "C" void kernel_launch(void* const* d_in, const int* in_sizes, int n_in,
                              void* d_out, int out_size, void* d_ws, size_t ws_size,
                              hipStream_t stream) {
    const float* x1 = (const float*)d_in[0];
    const float* x2 = (const float*)d_in[1];
    const int* ei1 = (const int*)d_in[2];
    const int* ei2 = (const int*)d_in[3];
    const float* l1_Wl = (const float*)d_in[4];
    const float* l1_bl = (const float*)d_in[5];
    const float* l1_Wr = (const float*)d_in[6];
    const float* l2_Wl = (const float*)d_in[7];
    const float* l2_bl = (const float*)d_in[8];
    const float* l2_Wr = (const float*)d_in[9];
    const float* l3_Wl = (const float*)d_in[10];
    const float* l3_bl = (const float*)d_in[11];
    const float* l3_Wr = (const float*)d_in[12];
    const float* W_w = (const float*)d_in[13];
    const float* W_b = (const float*)d_in[14];
    const float* W2_w = (const float*)d_in[15];
    const float* W2_b = (const float*)d_in[16];
    const float* prelu_a = (const float*)d_in[17];

    const int M = NN, E = NE;

    // ---- workspace layout (u16 units first, ints after) ----
    u16* wb = (u16*)d_ws;
    u16* Wr1t = wb;                        // [512,128]
    u16* Wl1t = Wr1t + 512 * 128;
    u16* Wwt  = Wl1t + 512 * 128;
    u16* W2wt = Wwt  + 512 * 128;
    u16* Wl2t = W2wt + 512 * 128;          // [512,512]
    u16* Wr2t = Wl2t + 512 * 512;
    u16* Wl3t = Wr2t + 512 * 512;
    u16* Wr3t = Wl3t + 512 * 512;
    u16* x_bf    = Wr3t + 512 * 512;       // [MPAD,128]
    u16* mean_bf = x_bf + (size_t)MPAD * DIN;      // [MPAD,512] (layer1 uses stride 128)
    u16* H_bf    = mean_bf + (size_t)MPAD * DH;
    u16* xin2_bf = H_bf    + (size_t)MPAD * DH;
    u16* xp3_bf  = xin2_bf + (size_t)MPAD * DH;
    u16* xin3_bf = xp3_bf  + (size_t)MPAD * DH;
    int* iws    = (int*)(xin3_bf + (size_t)MPAD * DH);
    int* deg    = iws;
    int* rowptr = iws + NN;
    int* cursor = iws + 2 * NN + 1;
    int* colx   = iws + 3 * NN + 1;

    float* out = (float*)d_out;

    // ---- weight transposes (once) ----
    dim3 wtb(32, 8);
    k_wt<<<dim3(16, 4),  wtb, 0, stream>>>(l1_Wr, Wr1t, DIN, DH);
    k_wt<<<dim3(16, 4),  wtb, 0, stream>>>(l1_Wl, Wl1t, DIN, DH);
    k_wt<<<dim3(16, 4),  wtb, 0, stream>>>(W_w,  Wwt,  DIN, DH);
    k_wt<<<dim3(16, 4),  wtb, 0, stream>>>(W2_w, W2wt, DIN, DH);
    k_wt<<<dim3(16, 16), wtb, 0, stream>>>(l2_Wl, Wl2t, DH, DH);
    k_wt<<<dim3(16, 16), wtb, 0, stream>>>(l2_Wr, Wr2t, DH, DH);
    k_wt<<<dim3(16, 16), wtb, 0, stream>>>(l3_Wl, Wl3t, DH, DH);
    k_wt<<<dim3(16, 16), wtb, 0, stream>>>(l3_Wr, Wr3t, DH, DH);

    dim3 gg(MPAD / 128, DH / 128);   // 391 x 4
    int aggGrid = (M + 3) / 4;

    for (int g = 0; g < 2; ++g) {
        const float* x = g ? x2 : x1;
        const int* ei = g ? ei2 : ei1;
        const int* src = ei;
        const int* dst = ei + E;
        float* z = out + (size_t)g * NN * DH;

        // CSR build
        k_zero_int<<<(M + 255) / 256, 256, 0, stream>>>(deg, M);
        k_deg<<<(E + 255) / 256, 256, 0, stream>>>(dst, deg, E);
        k_scan<<<1, 1024, 0, stream>>>(deg, rowptr, cursor, M);
        k_fill<<<(E + 255) / 256, 256, 0, stream>>>(src, dst, cursor, colx, E);

        // x -> bf16
        k_cast_bf<<<(M * DIN / 4 + 255) / 256, 256, 0, stream>>>(x, x_bf, M * DIN);

        // layer 1
        k_agg_bf<DIN><<<aggGrid, 256, 0, stream>>>(x_bf, rowptr, colx, mean_bf, M);
        // H = prelu(x@Wr1 + mean@Wl1 + bl1)
        k_mfma<128, 128, true, false, false><<<gg, 256, 0, stream>>>(
            x_bf, Wr1t, mean_bf, Wl1t, l1_bl, nullptr, prelu_a, nullptr, H_bf, M);
        // xin2 = x@W_w + W_b + H
        k_mfma<128, 0, false, true, false><<<gg, 256, 0, stream>>>(
            x_bf, Wwt, nullptr, nullptr, W_b, H_bf, prelu_a, nullptr, xin2_bf, M);
        // xp3 = x@W2_w + W2_b + H
        k_mfma<128, 0, false, true, false><<<gg, 256, 0, stream>>>(
            x_bf, W2wt, nullptr, nullptr, W2_b, H_bf, prelu_a, nullptr, xp3_bf, M);

        // layer 2
        k_agg_bf<DH><<<aggGrid, 256, 0, stream>>>(xin2_bf, rowptr, colx, mean_bf, M);
        // xin3 = prelu(mean2@Wl2 + xin2@Wr2 + bl2) + xp3
        k_mfma<512, 512, true, true, false><<<gg, 256, 0, stream>>>(
            mean_bf, Wl2t, xin2_bf, Wr2t, l2_bl, xp3_bf, prelu_a, nullptr, xin3_bf, M);

        // layer 3
        k_agg_bf<DH><<<aggGrid, 256, 0, stream>>>(xin3_bf, rowptr, colx, mean_bf, M);
        // z = prelu(mean3@Wl3 + xin3@Wr3 + bl3)
        k_mfma<512, 512, true, false, true><<<gg, 256, 0, stream>>>(
            mean_bf, Wl3t, xin3_bf, Wr3t, l3_bl, nullptr, prelu_a, z, nullptr, M);
    }
}

// Round 5
// 1554.234 us; speedup vs baseline: 2.5966x; 1.0279x over previous
//
#include <hip/hip_runtime.h>

// GLATE: 3-layer GraphSAGE encoder x2 graphs.
// Round 5: bf16 MFMA + double-buffered 2-phase K-pipeline + XCD-swizzled
// m-major 1D grid (A-panel L2 reuse). N=50000, E=400000, DIN=128, D=512.

#define NN 50000
#define NE 400000
#define DIN 128
#define DH 512
#define MPAD 50048   // 391*128, tile-padded row count for A-operand buffers

typedef __attribute__((ext_vector_type(4))) float f32x4;
typedef __attribute__((ext_vector_type(8))) short bf16x8;
typedef unsigned short u16;

__device__ __forceinline__ u16 f2bf(float f) {
    unsigned u = __float_as_uint(f);
    unsigned r = (u + 0x7fff + ((u >> 16) & 1)) >> 16;   // RNE
    return (u16)r;
}
__device__ __forceinline__ float bf2f(u16 b) {
    return __uint_as_float((unsigned)b << 16);
}

__device__ __forceinline__ void gload16(const void* g, void* l) {
    __builtin_amdgcn_global_load_lds(
        (const __attribute__((address_space(1))) unsigned int*)g,
        (__attribute__((address_space(3))) unsigned int*)l, 16, 0, 0);
}

// ---------------- CSR build ----------------

__global__ void k_zero_int(int* __restrict__ p, int n) {
    int i = blockIdx.x * 256 + threadIdx.x;
    if (i < n) p[i] = 0;
}

__global__ void k_deg(const int* __restrict__ dst, int* __restrict__ deg, int E) {
    int e = blockIdx.x * 256 + threadIdx.x;
    if (e < E) atomicAdd(&deg[dst[e]], 1);
}

__global__ void k_scan(const int* __restrict__ deg, int* __restrict__ rowptr,
                       int* __restrict__ cursor, int n) {
    __shared__ int buf[1024];
    __shared__ int carry;
    if (threadIdx.x == 0) carry = 0;
    __syncthreads();
    for (int base = 0; base < n; base += 1024) {
        int i = base + (int)threadIdx.x;
        int v = (i < n) ? deg[i] : 0;
        buf[threadIdx.x] = v;
        __syncthreads();
        for (int off = 1; off < 1024; off <<= 1) {
            int t = (threadIdx.x >= off) ? buf[threadIdx.x - off] : 0;
            __syncthreads();
            buf[threadIdx.x] += t;
            __syncthreads();
        }
        int excl = buf[threadIdx.x] - v;
        if (i < n) { rowptr[i] = carry + excl; cursor[i] = carry + excl; }
        __syncthreads();
        if (threadIdx.x == 1023) carry += buf[1023];
        __syncthreads();
    }
    if (threadIdx.x == 0) rowptr[n] = carry;
}

__global__ void k_fill(const int* __restrict__ src, const int* __restrict__ dst,
                       int* __restrict__ cursor, int* __restrict__ col, int E) {
    int e = blockIdx.x * 256 + threadIdx.x;
    if (e < E) {
        int p = atomicAdd(&cursor[dst[e]], 1);
        col[p] = src[e];
    }
}

// ---------------- f32 -> bf16 cast ----------------

__global__ void k_cast_bf(const float* __restrict__ x, u16* __restrict__ o, int n) {
    int i = (blockIdx.x * 256 + threadIdx.x) * 4;
    if (i + 3 < n) {
        float4 v = *(const float4*)&x[i];
        o[i + 0] = f2bf(v.x); o[i + 1] = f2bf(v.y);
        o[i + 2] = f2bf(v.z); o[i + 3] = f2bf(v.w);
    } else {
        for (int j = i; j < n; ++j) o[j] = f2bf(x[j]);
    }
}

// ---------------- weight transpose + cast: W[K,N] f32 -> Wt[N,K] bf16 ----------------

__global__ void k_wt(const float* __restrict__ W, u16* __restrict__ Wt, int K, int N) {
    __shared__ float t[32][33];
    int bn = blockIdx.x * 32;
    int bk = blockIdx.y * 32;
    int x = threadIdx.x;          // 0..31
    int y = threadIdx.y;          // 0..7
    for (int i = y; i < 32; i += 8) t[i][x] = W[(size_t)(bk + i) * N + bn + x];
    __syncthreads();
    for (int i = y; i < 32; i += 8)
        Wt[(size_t)(bn + i) * K + bk + x] = f2bf(t[x][i]);
}

// ---------------- mean aggregation over CSR, bf16 in/out, f32 accum ----------------
// one wave per node, 4 nodes per block

template<int D>
__global__ __launch_bounds__(256) void k_agg_bf(
        const u16* __restrict__ x, const int* __restrict__ rowptr,
        const int* __restrict__ col, u16* __restrict__ mean, int n) {
    int node = blockIdx.x * 4 + (threadIdx.x >> 6);
    if (node >= n) return;
    int lane = threadIdx.x & 63;
    int s = rowptr[node], e = rowptr[node + 1];
    float inv = (e > s) ? 1.0f / (float)(e - s) : 0.0f;
    if (D == 512) {
        float acc[8] = {};
        for (int j = s; j < e; ++j) {
            int r = col[j];
            uint4 v = *(const uint4*)(x + (size_t)r * D + lane * 8);
            unsigned w[4] = { v.x, v.y, v.z, v.w };
#pragma unroll
            for (int q = 0; q < 4; ++q) {
                acc[2 * q + 0] += bf2f((u16)(w[q] & 0xffff));
                acc[2 * q + 1] += bf2f((u16)(w[q] >> 16));
            }
        }
        unsigned o[4];
#pragma unroll
        for (int q = 0; q < 4; ++q)
            o[q] = (unsigned)f2bf(acc[2 * q] * inv) |
                   ((unsigned)f2bf(acc[2 * q + 1] * inv) << 16);
        *(uint4*)(mean + (size_t)node * D + lane * 8) = make_uint4(o[0], o[1], o[2], o[3]);
    } else {  // D == 128: 2 bf16 per lane
        float a0 = 0.f, a1 = 0.f;
        for (int j = s; j < e; ++j) {
            int r = col[j];
            unsigned v = *(const unsigned*)(x + (size_t)r * D + lane * 2);
            a0 += bf2f((u16)(v & 0xffff));
            a1 += bf2f((u16)(v >> 16));
        }
        unsigned o = (unsigned)f2bf(a0 * inv) | ((unsigned)f2bf(a1 * inv) << 16);
        *(unsigned*)(mean + (size_t)node * D + lane * 2) = o;
    }
}

// ---------------- MFMA GEMM, 2-phase double-buffered ----------------
// C[M,512] = maybe_prelu( A1@B1t' [+ A2@B2t'] + bias ) [+ addend]
// A row-major [MPAD,K] bf16; Bt row-major [512,K] bf16.
// 128x128 tile, 4 waves (2x2), 4x4 16x16x32 frags/wave, BK=32.
// 1D grid, m-major (n inner) + bijective XCD swizzle for A-panel L2 reuse.
// K-loop: STAGE(next) || ds_read+MFMA(cur), one __syncthreads per step.

#define MFMA_BF16(a, b, c) __builtin_amdgcn_mfma_f32_16x16x32_bf16(a, b, c, 0, 0, 0)

template<int K1, int K2, bool PRELU, bool ADDEND, bool OUTF32>
__global__ __launch_bounds__(256) void k_mfma(
        const u16* __restrict__ A1, const u16* __restrict__ B1t,
        const u16* __restrict__ A2, const u16* __restrict__ B2t,
        const float* __restrict__ bias, const u16* __restrict__ addend,
        const float* __restrict__ prelu_a,
        float* __restrict__ Cf, u16* __restrict__ Cb, int M) {
    __shared__ __align__(16) u16 As[2 * 128 * 32];   // 16 KB (2 buffers)
    __shared__ __align__(16) u16 Bs[2 * 128 * 32];

    constexpr int sK1 = K1 / 32;
    constexpr int sK2 = K2 / 32;
    constexpr int NS = sK1 + sK2;

    int tid = threadIdx.x;
    int wid = tid >> 6, lane = tid & 63;
    int wm = wid >> 1, wn = wid & 1;

    // bijective XCD swizzle (m204): consecutive logical tiles (n inner) land
    // on one XCD so the 4 n-blocks of an A-panel share its L2 fetch.
    int nwg = gridDim.x;
    int q = nwg >> 3, r = nwg & 7;
    int xcd = blockIdx.x & 7, idx = blockIdx.x >> 3;
    int swz = (xcd < r ? xcd * (q + 1) : r * (q + 1) + (xcd - r) * q) + idx;
    int m0 = (swz >> 2) * 128;
    int n0 = (swz & 3) * 128;

    f32x4 acc[4][4];
#pragma unroll
    for (int mi = 0; mi < 4; ++mi)
#pragma unroll
        for (int ni = 0; ni < 4; ++ni)
            acc[mi][ni] = (f32x4){0.f, 0.f, 0.f, 0.f};

    const int lm = lane & 15;        // frag row/col within 16
    const int ko = (lane >> 4) * 8;  // k element offset within BK=32

    auto stage = [&](int buf, int s) {
        const u16* A; const u16* Bt; int K, k0;
        if (s < sK1) { A = A1; Bt = B1t; K = K1; k0 = s * 32; }
        else         { A = A2; Bt = B2t; K = K2; k0 = (s - sK1) * 32; }
#pragma unroll
        for (int i = 0; i < 2; ++i) {
            int f = tid + i * 256;
            int row = f >> 2, seg = f & 3;
            gload16(A  + (size_t)(m0 + row) * K + k0 + seg * 8,
                    (char*)As + buf * 8192 + i * 4096 + wid * 1024);
            gload16(Bt + (size_t)(n0 + row) * K + k0 + seg * 8,
                    (char*)Bs + buf * 8192 + i * 4096 + wid * 1024);
        }
    };

    stage(0, 0);
    __syncthreads();                 // vmcnt(0) drain + barrier

    int cur = 0;
#pragma unroll 1
    for (int s = 0; s < NS; ++s) {
        if (s + 1 < NS) stage(cur ^ 1, s + 1);   // issue next tile early

        bf16x8 af[4], bfr[4];
#pragma unroll
        for (int x = 0; x < 4; ++x) {
            af[x]  = *(const bf16x8*)&As[cur * 4096 + (wm * 64 + x * 16 + lm) * 32 + ko];
            bfr[x] = *(const bf16x8*)&Bs[cur * 4096 + (wn * 64 + x * 16 + lm) * 32 + ko];
        }
#pragma unroll
        for (int mi = 0; mi < 4; ++mi)
#pragma unroll
            for (int ni = 0; ni < 4; ++ni)
                acc[mi][ni] = MFMA_BF16(af[mi], bfr[ni], acc[mi][ni]);

        __syncthreads();             // drains stage(s+1) loads + barrier
        cur ^= 1;
    }

    float aslope = PRELU ? *prelu_a : 0.f;
#pragma unroll
    for (int ni = 0; ni < 4; ++ni) {
        int colv = n0 + wn * 64 + ni * 16 + lm;
        float bv = bias[colv];
#pragma unroll
        for (int mi = 0; mi < 4; ++mi) {
            int rbase = m0 + wm * 64 + mi * 16 + (lane >> 4) * 4;
#pragma unroll
            for (int r2 = 0; r2 < 4; ++r2) {
                int gr = rbase + r2;
                if (gr >= M) continue;
                float v = acc[mi][ni][r2] + bv;
                if (PRELU) v = (v >= 0.f) ? v : aslope * v;
                if (ADDEND) v += bf2f(addend[(size_t)gr * DH + colv]);
                if (OUTF32) Cf[(size_t)gr * DH + colv] = v;
                else        Cb[(size_t)gr * DH + colv] = f2bf(v);
            }
        }
    }
}

// ---------------- launch ----------------

extern "C" void kernel_launch(void* const* d_in, const int* in_sizes, int n_in,
                              void* d_out, int out_size, void* d_ws, size_t ws_size,
                              hipStream_t stream) {
    const float* x1 = (const float*)d_in[0];
    const float* x2 = (const float*)d_in[1];
    const int* ei1 = (const int*)d_in[2];
    const int* ei2 = (const int*)d_in[3];
    const float* l1_Wl = (const float*)d_in[4];
    const float* l1_bl = (const float*)d_in[5];
    const float* l1_Wr = (const float*)d_in[6];
    const float* l2_Wl = (const float*)d_in[7];
    const float* l2_bl = (const float*)d_in[8];
    const float* l2_Wr = (const float*)d_in[9];
    const float* l3_Wl = (const float*)d_in[10];
    const float* l3_bl = (const float*)d_in[11];
    const float* l3_Wr = (const float*)d_in[12];
    const float* W_w = (const float*)d_in[13];
    const float* W_b = (const float*)d_in[14];
    const float* W2_w = (const float*)d_in[15];
    const float* W2_b = (const float*)d_in[16];
    const float* prelu_a = (const float*)d_in[17];

    const int M = NN, E = NE;

    // ---- workspace layout ----
    u16* wb = (u16*)d_ws;
    u16* Wr1t = wb;                        // [512,128]
    u16* Wl1t = Wr1t + 512 * 128;
    u16* Wwt  = Wl1t + 512 * 128;
    u16* W2wt = Wwt  + 512 * 128;
    u16* Wl2t = W2wt + 512 * 128;          // [512,512]
    u16* Wr2t = Wl2t + 512 * 512;
    u16* Wl3t = Wr2t + 512 * 512;
    u16* Wr3t = Wl3t + 512 * 512;
    u16* x_bf    = Wr3t + 512 * 512;       // [MPAD,128]
    u16* mean_bf = x_bf + (size_t)MPAD * DIN;      // [MPAD,512]
    u16* H_bf    = mean_bf + (size_t)MPAD * DH;
    u16* xin2_bf = H_bf    + (size_t)MPAD * DH;
    u16* xp3_bf  = xin2_bf + (size_t)MPAD * DH;
    u16* xin3_bf = xp3_bf  + (size_t)MPAD * DH;
    int* iws    = (int*)(xin3_bf + (size_t)MPAD * DH);
    int* deg    = iws;
    int* rowptr = iws + NN;
    int* cursor = iws + 2 * NN + 1;
    int* colx   = iws + 3 * NN + 1;

    float* out = (float*)d_out;

    // ---- weight transposes (once) ----
    dim3 wtb(32, 8);
    k_wt<<<dim3(16, 4),  wtb, 0, stream>>>(l1_Wr, Wr1t, DIN, DH);
    k_wt<<<dim3(16, 4),  wtb, 0, stream>>>(l1_Wl, Wl1t, DIN, DH);
    k_wt<<<dim3(16, 4),  wtb, 0, stream>>>(W_w,  Wwt,  DIN, DH);
    k_wt<<<dim3(16, 4),  wtb, 0, stream>>>(W2_w, W2wt, DIN, DH);
    k_wt<<<dim3(16, 16), wtb, 0, stream>>>(l2_Wl, Wl2t, DH, DH);
    k_wt<<<dim3(16, 16), wtb, 0, stream>>>(l2_Wr, Wr2t, DH, DH);
    k_wt<<<dim3(16, 16), wtb, 0, stream>>>(l3_Wl, Wl3t, DH, DH);
    k_wt<<<dim3(16, 16), wtb, 0, stream>>>(l3_Wr, Wr3t, DH, DH);

    const int nwg = (MPAD / 128) * (DH / 128);   // 391*4 = 1564, 1D swizzled
    int aggGrid = (M + 3) / 4;

    for (int g = 0; g < 2; ++g) {
        const float* x = g ? x2 : x1;
        const int* ei = g ? ei2 : ei1;
        const int* src = ei;
        const int* dst = ei + E;
        float* z = out + (size_t)g * NN * DH;

        // CSR build
        k_zero_int<<<(M + 255) / 256, 256, 0, stream>>>(deg, M);
        k_deg<<<(E + 255) / 256, 256, 0, stream>>>(dst, deg, E);
        k_scan<<<1, 1024, 0, stream>>>(deg, rowptr, cursor, M);
        k_fill<<<(E + 255) / 256, 256, 0, stream>>>(src, dst, cursor, colx, E);

        // x -> bf16
        k_cast_bf<<<(M * DIN / 4 + 255) / 256, 256, 0, stream>>>(x, x_bf, M * DIN);

        // layer 1
        k_agg_bf<DIN><<<aggGrid, 256, 0, stream>>>(x_bf, rowptr, colx, mean_bf, M);
        // H = prelu(x@Wr1 + mean@Wl1 + bl1)
        k_mfma<128, 128, true, false, false><<<nwg, 256, 0, stream>>>(
            x_bf, Wr1t, mean_bf, Wl1t, l1_bl, nullptr, prelu_a, nullptr, H_bf, M);
        // xin2 = x@W_w + W_b + H
        k_mfma<128, 0, false, true, false><<<nwg, 256, 0, stream>>>(
            x_bf, Wwt, nullptr, nullptr, W_b, H_bf, prelu_a, nullptr, xin2_bf, M);
        // xp3 = x@W2_w + W2_b + H
        k_mfma<128, 0, false, true, false><<<nwg, 256, 0, stream>>>(
            x_bf, W2wt, nullptr, nullptr, W2_b, H_bf, prelu_a, nullptr, xp3_bf, M);

        // layer 2
        k_agg_bf<DH><<<aggGrid, 256, 0, stream>>>(xin2_bf, rowptr, colx, mean_bf, M);
        // xin3 = prelu(mean2@Wl2 + xin2@Wr2 + bl2) + xp3
        k_mfma<512, 512, true, true, false><<<nwg, 256, 0, stream>>>(
            mean_bf, Wl2t, xin2_bf, Wr2t, l2_bl, xp3_bf, prelu_a, nullptr, xin3_bf, M);

        // layer 3
        k_agg_bf<DH><<<aggGrid, 256, 0, stream>>>(xin3_bf, rowptr, colx, mean_bf, M);
        // z = prelu(mean3@Wl3 + xin3@Wr3 + bl3)
        k_mfma<512, 512, true, false, true><<<nwg, 256, 0, stream>>>(
            mean_bf, Wl3t, xin3_bf, Wr3t, l3_bl, nullptr, prelu_a, z, nullptr, M);
    }
}